// Round 1
// baseline (8358.784 us; speedup 1.0000x reference)
//
#include <hip/hip_runtime.h>
#include <hip/hip_bf16.h>

// ---------------------------------------------------------------------------
// BERT forward (4 layers) + offset mean pooling, fp32 correctness baseline.
// B=8, S=1024, CH=512 -> NT=16 chunks, T=8192 token rows. D=768, H=12, dh=64,
// F=3072, L=4, W=512. Output: (8,512,768) fp32.
// Scratch lives in __device__ globals (no hipMalloc; graph-capture safe).
// Every buffer is fully written before read on every call.
// ---------------------------------------------------------------------------

#define TOK   8192      // total token rows (16 chunks x 512)
#define DMODEL 768
#define DFF   3072
#define NPAIR 192       // 16 chunks * 12 heads
#define SCH   512

__device__ float g_h  [TOK * DMODEL];
__device__ float g_q  [TOK * DMODEL];
__device__ float g_k  [TOK * DMODEL];
__device__ float g_v  [TOK * DMODEL];
__device__ float g_ctx[TOK * DMODEL];
__device__ float g_tmp[TOK * DMODEL];
__device__ float g_h1 [TOK * DMODEL];
__device__ float g_ff [TOK * DFF];
__device__ float g_sc [(size_t)NPAIR * SCH * SCH];   // 192 * 512 * 512 f32 = 201 MB

// ---------------------------------------------------------------------------
// helpers
// ---------------------------------------------------------------------------
__device__ inline float block_sum(float v, float* s4) {
#pragma unroll
    for (int o = 32; o > 0; o >>= 1) v += __shfl_down(v, o, 64);
    int lane = threadIdx.x & 63, w = threadIdx.x >> 6;
    __syncthreads();                 // protect s4 from previous use
    if (lane == 0) s4[w] = v;
    __syncthreads();
    return s4[0] + s4[1] + s4[2] + s4[3];
}

__device__ inline float block_max(float v, float* s4) {
#pragma unroll
    for (int o = 32; o > 0; o >>= 1) v = fmaxf(v, __shfl_down(v, o, 64));
    int lane = threadIdx.x & 63, w = threadIdx.x >> 6;
    __syncthreads();
    if (lane == 0) s4[w] = v;
    __syncthreads();
    return fmaxf(fmaxf(s4[0], s4[1]), fmaxf(s4[2], s4[3]));
}

__device__ inline float gelu_exact(float x) {
    return 0.5f * x * (1.f + erff(x * 0.70710678118654752f));
}

// ---------------------------------------------------------------------------
// embedding + LayerNorm  (one block per token row, 256 threads, 3 dims/thread)
// ---------------------------------------------------------------------------
__global__ __launch_bounds__(256) void embed_ln_kernel(
    const int* __restrict__ ids, const float* __restrict__ wemb,
    const float* __restrict__ pemb, const float* __restrict__ temb,
    const float* __restrict__ g, const float* __restrict__ b,
    float* __restrict__ out)
{
    int row = blockIdx.x;
    int pos = row & (SCH - 1);
    long id = ids[row];
    __shared__ float s4[4];
    float vals[3];
    float sum = 0.f;
#pragma unroll
    for (int i = 0; i < 3; i++) {
        int d = threadIdx.x + i * 256;
        float e = wemb[id * DMODEL + d] + pemb[pos * DMODEL + d] + temb[d];
        vals[i] = e; sum += e;
    }
    float mu = block_sum(sum, s4) * (1.f / DMODEL);
    float vs = 0.f;
#pragma unroll
    for (int i = 0; i < 3; i++) { float t = vals[i] - mu; vs += t * t; }
    float var = block_sum(vs, s4) * (1.f / DMODEL);
    float rstd = rsqrtf(var + 1e-12f);
#pragma unroll
    for (int i = 0; i < 3; i++) {
        int d = threadIdx.x + i * 256;
        out[(size_t)row * DMODEL + d] = (vals[i] - mu) * rstd * g[d] + b[d];
    }
}

// ---------------------------------------------------------------------------
// residual add + LayerNorm: out = LN(x + res)
// ---------------------------------------------------------------------------
__global__ __launch_bounds__(256) void add_ln_kernel(
    const float* __restrict__ x, const float* __restrict__ res,
    const float* __restrict__ g, const float* __restrict__ b,
    float* __restrict__ out)
{
    int row = blockIdx.x;
    const float* xr = x + (size_t)row * DMODEL;
    const float* rr = res + (size_t)row * DMODEL;
    __shared__ float s4[4];
    float vals[3];
    float sum = 0.f;
#pragma unroll
    for (int i = 0; i < 3; i++) {
        int d = threadIdx.x + i * 256;
        float e = xr[d] + rr[d];
        vals[i] = e; sum += e;
    }
    float mu = block_sum(sum, s4) * (1.f / DMODEL);
    float vs = 0.f;
#pragma unroll
    for (int i = 0; i < 3; i++) { float t = vals[i] - mu; vs += t * t; }
    float var = block_sum(vs, s4) * (1.f / DMODEL);
    float rstd = rsqrtf(var + 1e-12f);
#pragma unroll
    for (int i = 0; i < 3; i++) {
        int d = threadIdx.x + i * 256;
        out[(size_t)row * DMODEL + d] = (vals[i] - mu) * rstd * g[d] + b[d];
    }
}

// ---------------------------------------------------------------------------
// Generic fp32 GEMM, C = A @ B (+bias)(+gelu). 64x64 tile, 256 threads,
// 4x4 micro-tile per thread, K-tile 16. Batched via blockIdx.z with
// two-level offsets: off = (bz/bdiv)*s1 + (bz%bdiv)*s2.
// M, N multiples of 64; K multiple of 16 (true for all our shapes).
// ---------------------------------------------------------------------------
__global__ __launch_bounds__(256) void gemm_nn(
    const float* __restrict__ A, int lda, long long sA1, long long sA2,
    const float* __restrict__ B, int ldb, long long sB1, long long sB2,
    const float* __restrict__ bias,
    float* __restrict__ C, int ldc, long long sC1, long long sC2,
    int bdiv, int M, int N, int K, int act)
{
    int bz = blockIdx.z;
    long long zq = bz / bdiv, zr = bz % bdiv;
    A += zq * sA1 + zr * sA2;
    B += zq * sB1 + zr * sB2;
    C += zq * sC1 + zr * sC2;

    __shared__ float As[16][68];   // pad 68: store conflicts <=2-way, 16B-aligned rows
    __shared__ float Bs[16][64];

    int tid = threadIdx.x;
    int tx = tid & 15, ty = tid >> 4;
    int row0 = blockIdx.y * 64, col0 = blockIdx.x * 64;
    float acc[4][4] = {};

    for (int k0 = 0; k0 < K; k0 += 16) {
        {   // A tile 64x16 -> As[kk][r]
            int kk = tid & 15, r = tid >> 4;
#pragma unroll
            for (int p = 0; p < 4; p++)
                As[kk][r + p * 16] = A[(size_t)(row0 + r + p * 16) * lda + k0 + kk];
        }
        {   // B tile 16x64 -> Bs[kk][c]
            int c = tid & 63, kk = tid >> 6;
#pragma unroll
            for (int p = 0; p < 4; p++)
                Bs[kk + p * 4][c] = B[(size_t)(k0 + kk + p * 4) * ldb + col0 + c];
        }
        __syncthreads();
#pragma unroll
        for (int kk = 0; kk < 16; kk++) {
            const float4 a4 = *(const float4*)(&As[kk][ty * 4]);
            const float4 b4 = *(const float4*)(&Bs[kk][tx * 4]);
            float av[4] = {a4.x, a4.y, a4.z, a4.w};
            float bv[4] = {b4.x, b4.y, b4.z, b4.w};
#pragma unroll
            for (int i = 0; i < 4; i++)
#pragma unroll
                for (int j = 0; j < 4; j++)
                    acc[i][j] = fmaf(av[i], bv[j], acc[i][j]);
        }
        __syncthreads();
    }

#pragma unroll
    for (int i = 0; i < 4; i++) {
        int r = row0 + ty * 4 + i;
#pragma unroll
        for (int j = 0; j < 4; j++) {
            int cl = col0 + tx * 4 + j;
            float vv = acc[i][j];
            if (bias) vv += bias[cl];
            if (act == 1) vv = gelu_exact(vv);
            C[(size_t)r * ldc + cl] = vv;
        }
    }
}

// ---------------------------------------------------------------------------
// NT GEMM for scores: C[M,N] = A[M,K] @ B[N,K]^T  (no bias/act; raw dot)
// ---------------------------------------------------------------------------
__global__ __launch_bounds__(256) void gemm_nt(
    const float* __restrict__ A, int lda, long long sA1, long long sA2,
    const float* __restrict__ B, int ldb, long long sB1, long long sB2,
    float* __restrict__ C, int ldc, long long sC1, long long sC2,
    int bdiv, int M, int N, int K)
{
    int bz = blockIdx.z;
    long long zq = bz / bdiv, zr = bz % bdiv;
    A += zq * sA1 + zr * sA2;
    B += zq * sB1 + zr * sB2;
    C += zq * sC1 + zr * sC2;

    __shared__ float As[16][68];
    __shared__ float Bs[16][68];

    int tid = threadIdx.x;
    int tx = tid & 15, ty = tid >> 4;
    int row0 = blockIdx.y * 64, col0 = blockIdx.x * 64;
    float acc[4][4] = {};

    for (int k0 = 0; k0 < K; k0 += 16) {
        {
            int kk = tid & 15, r = tid >> 4;
#pragma unroll
            for (int p = 0; p < 4; p++)
                As[kk][r + p * 16] = A[(size_t)(row0 + r + p * 16) * lda + k0 + kk];
        }
        {
            int kk = tid & 15, c = tid >> 4;
#pragma unroll
            for (int p = 0; p < 4; p++)
                Bs[kk][c + p * 16] = B[(size_t)(col0 + c + p * 16) * ldb + k0 + kk];
        }
        __syncthreads();
#pragma unroll
        for (int kk = 0; kk < 16; kk++) {
            const float4 a4 = *(const float4*)(&As[kk][ty * 4]);
            const float4 b4 = *(const float4*)(&Bs[kk][tx * 4]);
            float av[4] = {a4.x, a4.y, a4.z, a4.w};
            float bv[4] = {b4.x, b4.y, b4.z, b4.w};
#pragma unroll
            for (int i = 0; i < 4; i++)
#pragma unroll
                for (int j = 0; j < 4; j++)
                    acc[i][j] = fmaf(av[i], bv[j], acc[i][j]);
        }
        __syncthreads();
    }

#pragma unroll
    for (int i = 0; i < 4; i++) {
        int r = row0 + ty * 4 + i;
#pragma unroll
        for (int j = 0; j < 4; j++) {
            int cl = col0 + tx * 4 + j;
            C[(size_t)r * ldc + cl] = acc[i][j];
        }
    }
}

// ---------------------------------------------------------------------------
// softmax over k (row of 512), applying scale and HF extended-mask bias.
// grid = NPAIR*512 blocks, 256 threads (2 elems/thread).
// ---------------------------------------------------------------------------
__global__ __launch_bounds__(256) void softmax_kernel(
    float* __restrict__ sc, const float* __restrict__ bmask, float scale)
{
    int pr = blockIdx.x;
    int pair = pr >> 9, row = pr & 511;
    int c = pair / 12;                     // chunk index
    float* p = sc + (size_t)pair * (SCH * SCH) + (size_t)row * SCH;
    const float* mrow = bmask + c * SCH;
    __shared__ float s4[4];
    float v[2];
#pragma unroll
    for (int i = 0; i < 2; i++) {
        int j = threadIdx.x + i * 256;
        v[i] = p[j] * scale + (1.f - mrow[j]) * (-10000.f);
    }
    float mx = block_max(fmaxf(v[0], v[1]), s4);
    float e0 = expf(v[0] - mx);
    float e1 = expf(v[1] - mx);
    float inv = 1.f / block_sum(e0 + e1, s4);
    p[threadIdx.x]       = e0 * inv;
    p[threadIdx.x + 256] = e1 * inv;
}

// ---------------------------------------------------------------------------
// offset mean pooling: out[b,w,:] = mean(h[b, st:ed, :]) if valid else 0
// grid = B*W = 4096 blocks, 256 threads (3 dims/thread).
// ---------------------------------------------------------------------------
__global__ __launch_bounds__(256) void pool_kernel(
    const float* __restrict__ h, const int* __restrict__ offs,
    const int* __restrict__ wmask, float* __restrict__ out)
{
    int bw = blockIdx.x;                   // b*512 + w
    int b = bw >> 9;
    int st = offs[bw * 2], ed = offs[bw * 2 + 1];
    bool valid = (wmask[bw] != 0) && (st < ed);
    float* orow = out + (size_t)bw * DMODEL;
    float inv = valid ? 1.f / (float)(ed - st) : 0.f;
#pragma unroll
    for (int i = 0; i < 3; i++) {
        int d = threadIdx.x + i * 256;
        float s = 0.f;
        if (valid) {
            for (int t = st; t < ed; t++)
                s += h[((size_t)b * 1024 + t) * DMODEL + d];
            s *= inv;
        }
        orow[d] = s;
    }
}

// ---------------------------------------------------------------------------
// host: launch pipeline
// ---------------------------------------------------------------------------
extern "C" void kernel_launch(void* const* d_in, const int* in_sizes, int n_in,
                              void* d_out, int out_size, void* d_ws, size_t ws_size,
                              hipStream_t stream) {
    const int*   x_bert   = (const int*)  d_in[0];
    const float* x_bmask  = (const float*)d_in[1];
    const int*   x_offset = (const int*)  d_in[2];
    const int*   x_wmask  = (const int*)  d_in[3];
    const float* wemb     = (const float*)d_in[4];
    const float* pemb     = (const float*)d_in[5];
    const float* temb     = (const float*)d_in[6];
    const float* emb_g    = (const float*)d_in[7];
    const float* emb_b    = (const float*)d_in[8];
    const float* Wq  = (const float*)d_in[9];
    const float* bq  = (const float*)d_in[10];
    const float* Wk  = (const float*)d_in[11];
    const float* bk  = (const float*)d_in[12];
    const float* Wv  = (const float*)d_in[13];
    const float* bv  = (const float*)d_in[14];
    const float* Wo  = (const float*)d_in[15];
    const float* bo  = (const float*)d_in[16];
    const float* ln1g = (const float*)d_in[17];
    const float* ln1b = (const float*)d_in[18];
    const float* W1  = (const float*)d_in[19];
    const float* b1f = (const float*)d_in[20];
    const float* W2  = (const float*)d_in[21];
    const float* b2f = (const float*)d_in[22];
    const float* ln2g = (const float*)d_in[23];
    const float* ln2b = (const float*)d_in[24];
    float* out = (float*)d_out;

    float *h, *q, *k, *v, *ctx, *tmp, *h1, *ff, *sc;
    hipGetSymbolAddress((void**)&h,   HIP_SYMBOL(g_h));
    hipGetSymbolAddress((void**)&q,   HIP_SYMBOL(g_q));
    hipGetSymbolAddress((void**)&k,   HIP_SYMBOL(g_k));
    hipGetSymbolAddress((void**)&v,   HIP_SYMBOL(g_v));
    hipGetSymbolAddress((void**)&ctx, HIP_SYMBOL(g_ctx));
    hipGetSymbolAddress((void**)&tmp, HIP_SYMBOL(g_tmp));
    hipGetSymbolAddress((void**)&h1,  HIP_SYMBOL(g_h1));
    hipGetSymbolAddress((void**)&ff,  HIP_SYMBOL(g_ff));
    hipGetSymbolAddress((void**)&sc,  HIP_SYMBOL(g_sc));

    // embedding + LN
    embed_ln_kernel<<<TOK, 256, 0, stream>>>(x_bert, wemb, pemb, temb, emb_g, emb_b, h);

    const long long sQ1 = (long long)SCH * DMODEL;   // chunk stride in q/k/v/ctx
    const long long sQ2 = 64;                        // head stride
    const long long sS1 = (long long)12 * SCH * SCH; // chunk stride in scores
    const long long sS2 = (long long)SCH * SCH;      // head stride in scores

    for (int l = 0; l < 4; l++) {
        const float* wq = Wq + (size_t)l * DMODEL * DMODEL;
        const float* wk = Wk + (size_t)l * DMODEL * DMODEL;
        const float* wv = Wv + (size_t)l * DMODEL * DMODEL;
        const float* wo = Wo + (size_t)l * DMODEL * DMODEL;
        const float* w1 = W1 + (size_t)l * DMODEL * DFF;
        const float* w2 = W2 + (size_t)l * DFF * DMODEL;
        const float* bql = bq + (size_t)l * DMODEL;
        const float* bkl = bk + (size_t)l * DMODEL;
        const float* bvl = bv + (size_t)l * DMODEL;
        const float* bol = bo + (size_t)l * DMODEL;
        const float* b1l = b1f + (size_t)l * DFF;
        const float* b2l = b2f + (size_t)l * DMODEL;
        const float* g1 = ln1g + (size_t)l * DMODEL;
        const float* be1 = ln1b + (size_t)l * DMODEL;
        const float* g2 = ln2g + (size_t)l * DMODEL;
        const float* be2 = ln2b + (size_t)l * DMODEL;

        dim3 gP(DMODEL / 64, TOK / 64, 1);       // 12 x 128
        gemm_nn<<<gP, 256, 0, stream>>>(h, DMODEL, 0, 0, wq, DMODEL, 0, 0, bql,
                                        q, DMODEL, 0, 0, 1, TOK, DMODEL, DMODEL, 0);
        gemm_nn<<<gP, 256, 0, stream>>>(h, DMODEL, 0, 0, wk, DMODEL, 0, 0, bkl,
                                        k, DMODEL, 0, 0, 1, TOK, DMODEL, DMODEL, 0);
        gemm_nn<<<gP, 256, 0, stream>>>(h, DMODEL, 0, 0, wv, DMODEL, 0, 0, bvl,
                                        v, DMODEL, 0, 0, 1, TOK, DMODEL, DMODEL, 0);

        // scores = Q K^T  per (chunk, head)
        dim3 gS(SCH / 64, SCH / 64, NPAIR);      // 8 x 8 x 192
        gemm_nt<<<gS, 256, 0, stream>>>(q, DMODEL, sQ1, sQ2,
                                        k, DMODEL, sQ1, sQ2,
                                        sc, SCH, sS1, sS2,
                                        12, SCH, SCH, 64);

        softmax_kernel<<<NPAIR * SCH, 256, 0, stream>>>(sc, x_bmask, 0.125f);

        // ctx = A V  per (chunk, head)
        dim3 gC(1, SCH / 64, NPAIR);
        gemm_nn<<<gC, 256, 0, stream>>>(sc, SCH, sS1, sS2,
                                        v, DMODEL, sQ1, sQ2, nullptr,
                                        ctx, DMODEL, sQ1, sQ2,
                                        12, SCH, 64, SCH, 0);

        // output projection + residual + LN1
        gemm_nn<<<gP, 256, 0, stream>>>(ctx, DMODEL, 0, 0, wo, DMODEL, 0, 0, bol,
                                        tmp, DMODEL, 0, 0, 1, TOK, DMODEL, DMODEL, 0);
        add_ln_kernel<<<TOK, 256, 0, stream>>>(tmp, h, g1, be1, h1);

        // FFN
        dim3 gF1(DFF / 64, TOK / 64, 1);         // 48 x 128
        gemm_nn<<<gF1, 256, 0, stream>>>(h1, DMODEL, 0, 0, w1, DFF, 0, 0, b1l,
                                         ff, DFF, 0, 0, 1, TOK, DFF, DMODEL, 1);
        gemm_nn<<<gP, 256, 0, stream>>>(ff, DFF, 0, 0, w2, DMODEL, 0, 0, b2l,
                                        tmp, DMODEL, 0, 0, 1, TOK, DMODEL, DFF, 0);
        add_ln_kernel<<<TOK, 256, 0, stream>>>(tmp, h1, g2, be2, h);
    }

    // pooling
    pool_kernel<<<8 * 512, 256, 0, stream>>>(h, x_offset, x_wmask, out);
}

// Round 2
// 1870.344 us; speedup vs baseline: 4.4691x; 4.4691x over previous
//
#include <hip/hip_runtime.h>
#include <hip/hip_bf16.h>

// ---------------------------------------------------------------------------
// BERT forward (4 layers) + offset mean pooling. bf16 MFMA GEMMs (m97-style:
// 128x128 tile, BK=64, global_load_lds width=16, xor-swizzled LDS k-groups),
// fp32 residual stream / LN / softmax statistics.
// ---------------------------------------------------------------------------

#define TOK   8192
#define DM    768
#define DQKV  2304
#define DF    3072
#define NPAIR 192
#define SCH   512

typedef __bf16 v8bf  __attribute__((ext_vector_type(8)));
typedef float  f32x4 __attribute__((ext_vector_type(4)));

// ------------------------------- scratch -----------------------------------
__device__ __align__(256) float g_h   [TOK * DM];
__device__ __align__(256) float g_h1  [TOK * DM];
__device__ __align__(256) float g_tmp [TOK * DM];
__device__ __align__(256) short g_hb  [TOK * DM];
__device__ __align__(256) short g_h1b [TOK * DM];
__device__ __align__(256) short g_qkv [TOK * DQKV];
__device__ __align__(256) short g_ctxb[TOK * DM];
__device__ __align__(256) short g_ffb [TOK * DF];
__device__ __align__(256) short g_vt  [(size_t)NPAIR * 64 * SCH];
__device__ __align__(256) short g_sb  [(size_t)NPAIR * SCH * SCH];
__device__ __align__(256) short g_pb  [(size_t)NPAIR * SCH * SCH];
__device__ __align__(256) short g_wqkvT[4 * (size_t)DQKV * DM];
__device__ __align__(256) short g_woT  [4 * (size_t)DM * DM];
__device__ __align__(256) short g_w1T  [4 * (size_t)DF * DM];
__device__ __align__(256) short g_w2T  [4 * (size_t)DM * DF];
__device__ __align__(256) float g_bqkv [4 * DQKV];

// ------------------------------ helpers ------------------------------------
__device__ __forceinline__ void g2l16(const short* g, short* l) {
    __builtin_amdgcn_global_load_lds(
        (const __attribute__((address_space(1))) void*)g,
        (__attribute__((address_space(3))) void*)l, 16, 0, 0);
}

__device__ inline float block_sum(float v, float* s4) {
#pragma unroll
    for (int o = 32; o > 0; o >>= 1) v += __shfl_down(v, o, 64);
    int lane = threadIdx.x & 63, w = threadIdx.x >> 6;
    __syncthreads();
    if (lane == 0) s4[w] = v;
    __syncthreads();
    return s4[0] + s4[1] + s4[2] + s4[3];
}

// ---------------------------------------------------------------------------
// weight transpose + bf16 convert: out[N][K] (bf16) = in[K][N] (fp32)
// grid (N/32, K/32, L), 256 threads
// ---------------------------------------------------------------------------
__global__ __launch_bounds__(256) void wconv(
    const float* __restrict__ in, short* __restrict__ out,
    int K, int N, long long inLS, long long outLS)
{
    in  += (size_t)blockIdx.z * inLS;
    out += (size_t)blockIdx.z * outLS;
    int k0 = blockIdx.y * 32, n0 = blockIdx.x * 32;
    __shared__ float s[32][33];
    int tr = threadIdx.x >> 5, tc = threadIdx.x & 31;
#pragma unroll
    for (int i = 0; i < 4; i++)
        s[tr + i * 8][tc] = in[(size_t)(k0 + tr + i * 8) * N + n0 + tc];
    __syncthreads();
    __hip_bfloat16* ob = (__hip_bfloat16*)out;
#pragma unroll
    for (int i = 0; i < 4; i++)
        ob[(size_t)(n0 + tr + i * 8) * K + k0 + tc] = __float2bfloat16(s[tc][tr + i * 8]);
}

__global__ __launch_bounds__(256) void concat_bias(
    const float* __restrict__ bq, const float* __restrict__ bk,
    const float* __restrict__ bv, float* __restrict__ out)
{
    int idx = blockIdx.x * 256 + threadIdx.x;
    if (idx >= 4 * DQKV) return;
    int l = idx / DQKV, n = idx % DQKV;
    float v = (n < 768) ? bq[l * 768 + n]
            : (n < 1536) ? bk[l * 768 + n - 768]
                         : bv[l * 768 + n - 1536];
    out[idx] = v;
}

// ---------------------------------------------------------------------------
// embedding + LN -> fp32 h + bf16 hb
// ---------------------------------------------------------------------------
__global__ __launch_bounds__(256) void embed_ln_kernel(
    const int* __restrict__ ids, const float* __restrict__ wemb,
    const float* __restrict__ pemb, const float* __restrict__ temb,
    const float* __restrict__ g, const float* __restrict__ b,
    float* __restrict__ outf, short* __restrict__ outb)
{
    int row = blockIdx.x;
    int pos = row & (SCH - 1);
    long id = ids[row];
    __shared__ float s4[4];
    float vals[3];
    float sum = 0.f;
#pragma unroll
    for (int i = 0; i < 3; i++) {
        int d = threadIdx.x + i * 256;
        float e = wemb[id * DM + d] + pemb[pos * DM + d] + temb[d];
        vals[i] = e; sum += e;
    }
    float mu = block_sum(sum, s4) * (1.f / DM);
    float vs = 0.f;
#pragma unroll
    for (int i = 0; i < 3; i++) { float t = vals[i] - mu; vs += t * t; }
    float rstd = rsqrtf(block_sum(vs, s4) * (1.f / DM) + 1e-12f);
    __hip_bfloat16* ob = (__hip_bfloat16*)outb;
#pragma unroll
    for (int i = 0; i < 3; i++) {
        int d = threadIdx.x + i * 256;
        float v = (vals[i] - mu) * rstd * g[d] + b[d];
        outf[(size_t)row * DM + d] = v;
        ob[(size_t)row * DM + d] = __float2bfloat16(v);
    }
}

// ---------------------------------------------------------------------------
// residual add + LN -> fp32 + bf16
// ---------------------------------------------------------------------------
__global__ __launch_bounds__(256) void add_ln_kernel(
    const float* __restrict__ x, const float* __restrict__ res,
    const float* __restrict__ g, const float* __restrict__ b,
    float* __restrict__ outf, short* __restrict__ outb)
{
    int row = blockIdx.x;
    const float* xr = x + (size_t)row * DM;
    const float* rr = res + (size_t)row * DM;
    __shared__ float s4[4];
    float vals[3];
    float sum = 0.f;
#pragma unroll
    for (int i = 0; i < 3; i++) {
        int d = threadIdx.x + i * 256;
        float e = xr[d] + rr[d];
        vals[i] = e; sum += e;
    }
    float mu = block_sum(sum, s4) * (1.f / DM);
    float vs = 0.f;
#pragma unroll
    for (int i = 0; i < 3; i++) { float t = vals[i] - mu; vs += t * t; }
    float rstd = rsqrtf(block_sum(vs, s4) * (1.f / DM) + 1e-12f);
    __hip_bfloat16* ob = (__hip_bfloat16*)outb;
#pragma unroll
    for (int i = 0; i < 3; i++) {
        int d = threadIdx.x + i * 256;
        float v = (vals[i] - mu) * rstd * g[d] + b[d];
        outf[(size_t)row * DM + d] = v;
        ob[(size_t)row * DM + d] = __float2bfloat16(v);
    }
}

// ---------------------------------------------------------------------------
// bf16 MFMA GEMM, C[M,N] = A[M,K] @ B[N,K]^T (+bias)(+gelu).
// BMxBN tile, BK=64, 4 waves (each 64x64), 16x16x32 bf16 MFMA.
// Staging: global_load_lds 16B/lane; k-groups xor-swizzled by row&7 so
// fragment ds_read_b128 hits the free 2-way bank-conflict regime.
// Batched via blockIdx.z: off = (bz/bdiv)*s1 + (bz%bdiv)*s2.
// Output: fp32 (Cf) or bf16 (Cb); act=1 applies exact GELU.
// ---------------------------------------------------------------------------
template<int BM, int BN>
__global__ __launch_bounds__(256) void mfma_gemm(
    const short* __restrict__ A, int lda, long long sA1, long long sA2,
    const short* __restrict__ B, int ldb, long long sB1, long long sB2,
    const float* __restrict__ bias,
    float* __restrict__ Cf, short* __restrict__ Cb, int ldc,
    long long sC1, long long sC2, int bdiv, int K, int act)
{
    constexpr int WCOLS = BN / 64;
    __shared__ __align__(16) short As[BM * 64];
    __shared__ __align__(16) short Bs[BN * 64];

    int bz = blockIdx.z;
    long long zq = bz / bdiv, zr = bz % bdiv;
    A += zq * sA1 + zr * sA2;
    B += zq * sB1 + zr * sB2;
    const long long coff = zq * sC1 + zr * sC2;

    const int tid = threadIdx.x;
    const int w = tid >> 6, l = tid & 63;
    const int lr = l >> 3, lc = l & 7;     // staging: row-in-chunk, k-group
    const int lcs = lc ^ lr;               // xor-swizzled source k-group
    const int quad = l >> 4, m16 = l & 15;
    const int wm0 = (w / WCOLS) * 64, wn0 = (w % WCOLS) * 64;
    const int row0 = blockIdx.y * BM, col0 = blockIdx.x * BN;

    f32x4 acc[4][4] = {};

    for (int k0 = 0; k0 < K; k0 += 64) {
#pragma unroll
        for (int i = 0; i < BM / 32; i++) {
            int ch = w * (BM / 32) + i;
            g2l16(A + (size_t)(row0 + ch * 8 + lr) * lda + k0 + lcs * 8,
                  As + ch * 512 + l * 8);
        }
#pragma unroll
        for (int i = 0; i < BN / 32; i++) {
            int ch = w * (BN / 32) + i;
            g2l16(B + (size_t)(col0 + ch * 8 + lr) * ldb + k0 + lcs * 8,
                  Bs + ch * 512 + l * 8);
        }
        __syncthreads();
#pragma unroll
        for (int ks = 0; ks < 2; ks++) {
            int g = ks * 4 + quad;
            v8bf af[4], bfr[4];
#pragma unroll
            for (int rb = 0; rb < 4; rb++) {
                int r = wm0 + rb * 16 + m16;
                af[rb] = *(const v8bf*)&As[r * 64 + ((g ^ (r & 7)) << 3)];
            }
#pragma unroll
            for (int cb = 0; cb < 4; cb++) {
                int r = wn0 + cb * 16 + m16;
                bfr[cb] = *(const v8bf*)&Bs[r * 64 + ((g ^ (r & 7)) << 3)];
            }
#pragma unroll
            for (int rb = 0; rb < 4; rb++)
#pragma unroll
                for (int cb = 0; cb < 4; cb++)
                    acc[rb][cb] = __builtin_amdgcn_mfma_f32_16x16x32_bf16(
                        af[rb], bfr[cb], acc[rb][cb], 0, 0, 0);
        }
        __syncthreads();
    }

    float* cf = Cf ? Cf + coff : nullptr;
    __hip_bfloat16* cbp = Cb ? (__hip_bfloat16*)Cb + coff : nullptr;
#pragma unroll
    for (int cb = 0; cb < 4; cb++) {
        int col = col0 + wn0 + cb * 16 + m16;
        float bvv = bias ? bias[col] : 0.f;
#pragma unroll
        for (int rb = 0; rb < 4; rb++) {
            int rbase = row0 + wm0 + rb * 16 + quad * 4;
#pragma unroll
            for (int r = 0; r < 4; r++) {
                float v = acc[rb][cb][r] + bvv;
                if (act) v = 0.5f * v * (1.f + erff(v * 0.70710678118654752f));
                size_t off = (size_t)(rbase + r) * ldc + col;
                if (cf) cf[off] = v;
                else    cbp[off] = __float2bfloat16(v);
            }
        }
    }
}

// ---------------------------------------------------------------------------
// softmax: one wave per row of 512. sb(bf16) -> pb(bf16), scale + HF mask.
// grid = NPAIR*SCH/4 blocks, 256 threads.
// ---------------------------------------------------------------------------
__global__ __launch_bounds__(256) void softmax_bf16(
    const short* __restrict__ sb, short* __restrict__ pb,
    const float* __restrict__ bmask)
{
    int w = threadIdx.x >> 6, l = threadIdx.x & 63;
    int r = blockIdx.x * 4 + w;
    int pair = r >> 9, row = r & 511;
    int chunk = pair / 12;
    size_t off = (size_t)pair * (SCH * SCH) + (size_t)row * SCH;
    const __hip_bfloat16* p = (const __hip_bfloat16*)sb + off;
    const float* mrow = bmask + chunk * SCH;
    float v[8];
    float mx = -1e30f;
#pragma unroll
    for (int i = 0; i < 8; i++) {
        int j = l + i * 64;
        v[i] = __bfloat162float(p[j]) * 0.125f + (1.f - mrow[j]) * (-10000.f);
        mx = fmaxf(mx, v[i]);
    }
#pragma unroll
    for (int o = 32; o > 0; o >>= 1) mx = fmaxf(mx, __shfl_down(mx, o, 64));
    mx = __shfl(mx, 0, 64);
    float s = 0.f;
#pragma unroll
    for (int i = 0; i < 8; i++) { v[i] = expf(v[i] - mx); s += v[i]; }
#pragma unroll
    for (int o = 32; o > 0; o >>= 1) s += __shfl_down(s, o, 64);
    s = __shfl(s, 0, 64);
    float inv = 1.f / s;
    __hip_bfloat16* q = (__hip_bfloat16*)pb + off;
#pragma unroll
    for (int i = 0; i < 8; i++) q[l + i * 64] = __float2bfloat16(v[i] * inv);
}

// ---------------------------------------------------------------------------
// V transpose: qkv v-section [chunk*512+t][1536 + head*64 + d] ->
// vt[(pair*64 + d)*512 + t]. grid (8, NPAIR), 256 threads, 64x64 tiles.
// ---------------------------------------------------------------------------
__global__ __launch_bounds__(256) void transpose_v(
    const short* __restrict__ qkv, short* __restrict__ vt)
{
    int pair = blockIdx.y, chunk = pair / 12, head = pair % 12;
    int t0 = blockIdx.x * 64;
    __shared__ short s[64][68];
    int tr = threadIdx.x >> 4;
    int tc = (threadIdx.x & 15) * 4;
    const short* src = qkv + 1536 + (size_t)(chunk * SCH + t0) * DQKV + head * 64;
#pragma unroll
    for (int i = 0; i < 4; i++) {
        int t = tr + i * 16;
        ushort4 u = *(const ushort4*)(src + (size_t)t * DQKV + tc);
        s[t][tc] = u.x; s[t][tc + 1] = u.y; s[t][tc + 2] = u.z; s[t][tc + 3] = u.w;
    }
    __syncthreads();
    short* dst = vt + (size_t)pair * 64 * SCH + t0;
#pragma unroll
    for (int i = 0; i < 4; i++) {
        int d = tr + i * 16;
        ushort4 o;
        o.x = s[tc][d]; o.y = s[tc + 1][d]; o.z = s[tc + 2][d]; o.w = s[tc + 3][d];
        *(ushort4*)(dst + (size_t)d * SCH + tc) = o;
    }
}

// ---------------------------------------------------------------------------
// offset mean pooling over fp32 h
// ---------------------------------------------------------------------------
__global__ __launch_bounds__(256) void pool_kernel(
    const float* __restrict__ h, const int* __restrict__ offs,
    const int* __restrict__ wmask, float* __restrict__ out)
{
    int bw = blockIdx.x;
    int b = bw >> 9;
    int st = offs[bw * 2], ed = offs[bw * 2 + 1];
    bool valid = (wmask[bw] != 0) && (st < ed);
    float* orow = out + (size_t)bw * DM;
    float inv = valid ? 1.f / (float)(ed - st) : 0.f;
#pragma unroll
    for (int i = 0; i < 3; i++) {
        int d = threadIdx.x + i * 256;
        float s = 0.f;
        if (valid) {
            for (int t = st; t < ed; t++)
                s += h[((size_t)b * 1024 + t) * DM + d];
            s *= inv;
        }
        orow[d] = s;
    }
}

// ---------------------------------------------------------------------------
// host pipeline
// ---------------------------------------------------------------------------
extern "C" void kernel_launch(void* const* d_in, const int* in_sizes, int n_in,
                              void* d_out, int out_size, void* d_ws, size_t ws_size,
                              hipStream_t stream) {
    const int*   x_bert   = (const int*)  d_in[0];
    const float* x_bmask  = (const float*)d_in[1];
    const int*   x_offset = (const int*)  d_in[2];
    const int*   x_wmask  = (const int*)  d_in[3];
    const float* wemb     = (const float*)d_in[4];
    const float* pemb     = (const float*)d_in[5];
    const float* temb     = (const float*)d_in[6];
    const float* emb_g    = (const float*)d_in[7];
    const float* emb_b    = (const float*)d_in[8];
    const float* Wq  = (const float*)d_in[9];
    const float* bq  = (const float*)d_in[10];
    const float* Wk  = (const float*)d_in[11];
    const float* bk  = (const float*)d_in[12];
    const float* Wv  = (const float*)d_in[13];
    const float* bv  = (const float*)d_in[14];
    const float* Wo  = (const float*)d_in[15];
    const float* bo  = (const float*)d_in[16];
    const float* ln1g = (const float*)d_in[17];
    const float* ln1b = (const float*)d_in[18];
    const float* W1  = (const float*)d_in[19];
    const float* b1f = (const float*)d_in[20];
    const float* W2  = (const float*)d_in[21];
    const float* b2f = (const float*)d_in[22];
    const float* ln2g = (const float*)d_in[23];
    const float* ln2b = (const float*)d_in[24];
    float* out = (float*)d_out;

    float *h, *h1, *tmp, *bqkv;
    short *hb, *h1b, *qkv, *ctxb, *ffb, *vt, *sb, *pb, *wqkvT, *woT, *w1T, *w2T;
    hipGetSymbolAddress((void**)&h,    HIP_SYMBOL(g_h));
    hipGetSymbolAddress((void**)&h1,   HIP_SYMBOL(g_h1));
    hipGetSymbolAddress((void**)&tmp,  HIP_SYMBOL(g_tmp));
    hipGetSymbolAddress((void**)&hb,   HIP_SYMBOL(g_hb));
    hipGetSymbolAddress((void**)&h1b,  HIP_SYMBOL(g_h1b));
    hipGetSymbolAddress((void**)&qkv,  HIP_SYMBOL(g_qkv));
    hipGetSymbolAddress((void**)&ctxb, HIP_SYMBOL(g_ctxb));
    hipGetSymbolAddress((void**)&ffb,  HIP_SYMBOL(g_ffb));
    hipGetSymbolAddress((void**)&vt,   HIP_SYMBOL(g_vt));
    hipGetSymbolAddress((void**)&sb,   HIP_SYMBOL(g_sb));
    hipGetSymbolAddress((void**)&pb,   HIP_SYMBOL(g_pb));
    hipGetSymbolAddress((void**)&wqkvT,HIP_SYMBOL(g_wqkvT));
    hipGetSymbolAddress((void**)&woT,  HIP_SYMBOL(g_woT));
    hipGetSymbolAddress((void**)&w1T,  HIP_SYMBOL(g_w1T));
    hipGetSymbolAddress((void**)&w2T,  HIP_SYMBOL(g_w2T));
    hipGetSymbolAddress((void**)&bqkv, HIP_SYMBOL(g_bqkv));

    // ---- weight prep (per call; ~27 us of traffic) ----
    dim3 wtA(DM / 32, DM / 32, 4);
    wconv<<<wtA, 256, 0, stream>>>(Wq, wqkvT,              DM, DM, (long long)DM * DM, (long long)DQKV * DM);
    wconv<<<wtA, 256, 0, stream>>>(Wk, wqkvT + 768 * DM,   DM, DM, (long long)DM * DM, (long long)DQKV * DM);
    wconv<<<wtA, 256, 0, stream>>>(Wv, wqkvT + 1536 * DM,  DM, DM, (long long)DM * DM, (long long)DQKV * DM);
    wconv<<<wtA, 256, 0, stream>>>(Wo, woT,                DM, DM, (long long)DM * DM, (long long)DM * DM);
    dim3 wtB(DF / 32, DM / 32, 4);
    wconv<<<wtB, 256, 0, stream>>>(W1, w1T, DM, DF, (long long)DM * DF, (long long)DF * DM);
    dim3 wtC(DM / 32, DF / 32, 4);
    wconv<<<wtC, 256, 0, stream>>>(W2, w2T, DF, DM, (long long)DF * DM, (long long)DM * DF);
    concat_bias<<<(4 * DQKV + 255) / 256, 256, 0, stream>>>(bq, bk, bv, bqkv);

    // ---- embedding ----
    embed_ln_kernel<<<TOK, 256, 0, stream>>>(x_bert, wemb, pemb, temb, emb_g, emb_b, h, hb);

    const long long sQ1 = (long long)SCH * DQKV;  // chunk stride in qkv rows
    const long long sS1 = 12LL * SCH * SCH;       // chunk stride in scores
    const long long sS2 = (long long)SCH * SCH;   // head stride in scores
    const long long sV1 = 12LL * 64 * SCH;        // chunk stride in vt
    const long long sV2 = 64LL * SCH;             // head stride in vt

    for (int l = 0; l < 4; l++) {
        const short* wqkvl = wqkvT + (size_t)l * DQKV * DM;
        const short* wol   = woT  + (size_t)l * DM * DM;
        const short* w1l   = w1T  + (size_t)l * DF * DM;
        const short* w2l   = w2T  + (size_t)l * DM * DF;

        // fused QKV projection: [8192,768] x [2304,768]^T -> bf16 qkv
        mfma_gemm<128, 128><<<dim3(DQKV / 128, TOK / 128, 1), 256, 0, stream>>>(
            hb, DM, 0, 0, wqkvl, DM, 0, 0, bqkv + l * DQKV,
            nullptr, qkv, DQKV, 0, 0, 1, DM, 0);

        // scores = Q K^T per (chunk, head): M=N=512, K=64 -> bf16 sb
        mfma_gemm<128, 128><<<dim3(4, 4, NPAIR), 256, 0, stream>>>(
            qkv,       DQKV, sQ1, 64,
            qkv + 768, DQKV, sQ1, 64,
            nullptr, nullptr, sb, SCH, sS1, sS2, 12, 64, 0);

        softmax_bf16<<<NPAIR * SCH / 4, 256, 0, stream>>>(sb, pb, x_bmask);

        transpose_v<<<dim3(8, NPAIR), 256, 0, stream>>>(qkv, vt);

        // ctx = P V per (chunk, head): M=512, N=64, K=512 -> bf16 ctxb
        mfma_gemm<256, 64><<<dim3(1, 2, NPAIR), 256, 0, stream>>>(
            pb, SCH, sS1, sS2,
            vt, SCH, sV1, sV2,
            nullptr, nullptr, ctxb, DM, (long long)SCH * DM, 64, 12, SCH, 0);

        // output projection -> fp32 tmp
        mfma_gemm<128, 128><<<dim3(DM / 128, TOK / 128, 1), 256, 0, stream>>>(
            ctxb, DM, 0, 0, wol, DM, 0, 0, bo + (size_t)l * DM,
            tmp, nullptr, DM, 0, 0, 1, DM, 0);
        add_ln_kernel<<<TOK, 256, 0, stream>>>(tmp, h, ln1g + (size_t)l * DM, ln1b + (size_t)l * DM, h1, h1b);

        // FFN1 (+gelu) -> bf16 ffb
        mfma_gemm<128, 128><<<dim3(DF / 128, TOK / 128, 1), 256, 0, stream>>>(
            h1b, DM, 0, 0, w1l, DM, 0, 0, b1f + (size_t)l * DF,
            nullptr, ffb, DF, 0, 0, 1, DM, 1);
        // FFN2 -> fp32 tmp
        mfma_gemm<128, 128><<<dim3(DM / 128, TOK / 128, 1), 256, 0, stream>>>(
            ffb, DF, 0, 0, w2l, DF, 0, 0, b2f + (size_t)l * DM,
            tmp, nullptr, DM, 0, 0, 1, DF, 0);
        add_ln_kernel<<<TOK, 256, 0, stream>>>(tmp, h1, ln2g + (size_t)l * DM, ln2b + (size_t)l * DM, h, hb);
    }

    pool_kernel<<<8 * 512, 256, 0, stream>>>(h, x_offset, x_wmask, out);
}

// Round 3
// 1787.197 us; speedup vs baseline: 4.6770x; 1.0465x over previous
//
#include <hip/hip_runtime.h>
#include <hip/hip_bf16.h>

// ---------------------------------------------------------------------------
// BERT forward (4 layers) + offset mean pooling.
// Round 3: (1) single-barrier double-buffered K-loop in the bf16 MFMA GEMM
// (1-iter prefetch lookahead so the vmcnt drain waits on loads issued a full
// MFMA phase earlier); (2) fused flash attention (replaces scores GEMM +
// softmax + ctx GEMM); (3) residual add fused into O-proj/FFN2 epilogues.
// ---------------------------------------------------------------------------

#define TOK   8192
#define DM    768
#define DQKV  2304
#define DF    3072
#define NPAIR 192
#define SCH   512

typedef __bf16 v8bf  __attribute__((ext_vector_type(8)));
typedef float  f32x4 __attribute__((ext_vector_type(4)));

// ------------------------------- scratch -----------------------------------
__device__ __align__(256) float g_h   [TOK * DM];
__device__ __align__(256) float g_h1  [TOK * DM];
__device__ __align__(256) float g_tmp [TOK * DM];
__device__ __align__(256) short g_hb  [TOK * DM];
__device__ __align__(256) short g_h1b [TOK * DM];
__device__ __align__(256) short g_qkv [TOK * DQKV];
__device__ __align__(256) short g_ctxb[TOK * DM];
__device__ __align__(256) short g_ffb [TOK * DF];
__device__ __align__(256) short g_vt  [(size_t)NPAIR * 64 * SCH];
__device__ __align__(256) short g_wqkvT[4 * (size_t)DQKV * DM];
__device__ __align__(256) short g_woT  [4 * (size_t)DM * DM];
__device__ __align__(256) short g_w1T  [4 * (size_t)DF * DM];
__device__ __align__(256) short g_w2T  [4 * (size_t)DM * DF];
__device__ __align__(256) float g_bqkv [4 * DQKV];

// ------------------------------ helpers ------------------------------------
__device__ __forceinline__ void g2l16(const short* g, short* l) {
    __builtin_amdgcn_global_load_lds(
        (const __attribute__((address_space(1))) void*)g,
        (__attribute__((address_space(3))) void*)l, 16, 0, 0);
}

__device__ inline float block_sum(float v, float* s4) {
#pragma unroll
    for (int o = 32; o > 0; o >>= 1) v += __shfl_down(v, o, 64);
    int lane = threadIdx.x & 63, w = threadIdx.x >> 6;
    __syncthreads();
    if (lane == 0) s4[w] = v;
    __syncthreads();
    return s4[0] + s4[1] + s4[2] + s4[3];
}

// ---------------------------------------------------------------------------
// weight transpose + bf16 convert: out[N][K] (bf16) = in[K][N] (fp32)
// ---------------------------------------------------------------------------
__global__ __launch_bounds__(256) void wconv(
    const float* __restrict__ in, short* __restrict__ out,
    int K, int N, long long inLS, long long outLS)
{
    in  += (size_t)blockIdx.z * inLS;
    out += (size_t)blockIdx.z * outLS;
    int k0 = blockIdx.y * 32, n0 = blockIdx.x * 32;
    __shared__ float s[32][33];
    int tr = threadIdx.x >> 5, tc = threadIdx.x & 31;
#pragma unroll
    for (int i = 0; i < 4; i++)
        s[tr + i * 8][tc] = in[(size_t)(k0 + tr + i * 8) * N + n0 + tc];
    __syncthreads();
    __hip_bfloat16* ob = (__hip_bfloat16*)out;
#pragma unroll
    for (int i = 0; i < 4; i++)
        ob[(size_t)(n0 + tr + i * 8) * K + k0 + tc] = __float2bfloat16(s[tc][tr + i * 8]);
}

__global__ __launch_bounds__(256) void concat_bias(
    const float* __restrict__ bq, const float* __restrict__ bk,
    const float* __restrict__ bv, float* __restrict__ out)
{
    int idx = blockIdx.x * 256 + threadIdx.x;
    if (idx >= 4 * DQKV) return;
    int l = idx / DQKV, n = idx % DQKV;
    float v = (n < 768) ? bq[l * 768 + n]
            : (n < 1536) ? bk[l * 768 + n - 768]
                         : bv[l * 768 + n - 1536];
    out[idx] = v;
}

// ---------------------------------------------------------------------------
// embedding + LN -> fp32 h + bf16 hb
// ---------------------------------------------------------------------------
__global__ __launch_bounds__(256) void embed_ln_kernel(
    const int* __restrict__ ids, const float* __restrict__ wemb,
    const float* __restrict__ pemb, const float* __restrict__ temb,
    const float* __restrict__ g, const float* __restrict__ b,
    float* __restrict__ outf, short* __restrict__ outb)
{
    int row = blockIdx.x;
    int pos = row & (SCH - 1);
    long id = ids[row];
    __shared__ float s4[4];
    float vals[3];
    float sum = 0.f;
#pragma unroll
    for (int i = 0; i < 3; i++) {
        int d = threadIdx.x + i * 256;
        float e = wemb[id * DM + d] + pemb[pos * DM + d] + temb[d];
        vals[i] = e; sum += e;
    }
    float mu = block_sum(sum, s4) * (1.f / DM);
    float vs = 0.f;
#pragma unroll
    for (int i = 0; i < 3; i++) { float t = vals[i] - mu; vs += t * t; }
    float rstd = rsqrtf(block_sum(vs, s4) * (1.f / DM) + 1e-12f);
    __hip_bfloat16* ob = (__hip_bfloat16*)outb;
#pragma unroll
    for (int i = 0; i < 3; i++) {
        int d = threadIdx.x + i * 256;
        float v = (vals[i] - mu) * rstd * g[d] + b[d];
        outf[(size_t)row * DM + d] = v;
        ob[(size_t)row * DM + d] = __float2bfloat16(v);
    }
}

// ---------------------------------------------------------------------------
// pure LN (input already contains residual): out = LN(x)
// ---------------------------------------------------------------------------
__global__ __launch_bounds__(256) void ln_kernel(
    const float* __restrict__ x,
    const float* __restrict__ g, const float* __restrict__ b,
    float* __restrict__ outf, short* __restrict__ outb)
{
    int row = blockIdx.x;
    const float* xr = x + (size_t)row * DM;
    __shared__ float s4[4];
    float vals[3];
    float sum = 0.f;
#pragma unroll
    for (int i = 0; i < 3; i++) {
        int d = threadIdx.x + i * 256;
        float e = xr[d];
        vals[i] = e; sum += e;
    }
    float mu = block_sum(sum, s4) * (1.f / DM);
    float vs = 0.f;
#pragma unroll
    for (int i = 0; i < 3; i++) { float t = vals[i] - mu; vs += t * t; }
    float rstd = rsqrtf(block_sum(vs, s4) * (1.f / DM) + 1e-12f);
    __hip_bfloat16* ob = (__hip_bfloat16*)outb;
#pragma unroll
    for (int i = 0; i < 3; i++) {
        int d = threadIdx.x + i * 256;
        float v = (vals[i] - mu) * rstd * g[d] + b[d];
        outf[(size_t)row * DM + d] = v;
        ob[(size_t)row * DM + d] = __float2bfloat16(v);
    }
}

// ---------------------------------------------------------------------------
// bf16 MFMA GEMM, C[M,N] = A[M,K] @ B[N,K]^T (+bias)(+res)(+gelu).
// 128x128 tile, BK=64, 4 waves of 64x64, 16x16x32 MFMA.
// Double-buffered LDS, ONE barrier per iter: prefetch for tile k+1 is issued
// right after the barrier, so the vmcnt drain at the NEXT barrier waits on
// loads that overlapped a full MFMA phase. Xor-swizzled k-groups keep
// ds_read_b128 in the free 2-way conflict regime.
// ---------------------------------------------------------------------------
__global__ __launch_bounds__(256) void mfma_gemm(
    const short* __restrict__ A, int lda,
    const short* __restrict__ B, int ldb,
    const float* __restrict__ bias, const float* __restrict__ res,
    float* __restrict__ Cf, short* __restrict__ Cb, int ldc, int K, int act)
{
    __shared__ __align__(16) short As[2][128 * 64];
    __shared__ __align__(16) short Bs[2][128 * 64];

    const int tid = threadIdx.x;
    const int w = tid >> 6, l = tid & 63;
    const int lr = l >> 3, lc = l & 7;
    const int lcs = lc ^ lr;               // xor-swizzled source k-group
    const int quad = l >> 4, m16 = l & 15;
    const int wm0 = (w >> 1) * 64, wn0 = (w & 1) * 64;
    const int row0 = blockIdx.y * 128, col0 = blockIdx.x * 128;

    const short* Abase = A + (size_t)(row0 + lr) * lda + lcs * 8;
    const short* Bbase = B + (size_t)(col0 + lr) * ldb + lcs * 8;

    auto stage = [&](int k0, int buf) {
#pragma unroll
        for (int i = 0; i < 4; i++) {
            int ch = w * 4 + i;
            g2l16(Abase + (size_t)ch * 8 * lda + k0, &As[buf][ch * 512 + l * 8]);
        }
#pragma unroll
        for (int i = 0; i < 4; i++) {
            int ch = w * 4 + i;
            g2l16(Bbase + (size_t)ch * 8 * ldb + k0, &Bs[buf][ch * 512 + l * 8]);
        }
    };

    f32x4 acc[4][4] = {};
    stage(0, 0);
    const int nk = K >> 6;
    for (int kk = 0; kk < nk; kk++) {
        __syncthreads();                       // drains loads issued last iter
        if (kk + 1 < nk) stage((kk + 1) << 6, (kk + 1) & 1);
        const short* as = As[kk & 1];
        const short* bs = Bs[kk & 1];
#pragma unroll
        for (int ks = 0; ks < 2; ks++) {
            int g = ks * 4 + quad;
            v8bf af[4], bfr[4];
#pragma unroll
            for (int rb = 0; rb < 4; rb++) {
                int r = wm0 + rb * 16 + m16;
                af[rb] = *(const v8bf*)&as[r * 64 + ((g ^ (r & 7)) << 3)];
            }
#pragma unroll
            for (int cb = 0; cb < 4; cb++) {
                int r = wn0 + cb * 16 + m16;
                bfr[cb] = *(const v8bf*)&bs[r * 64 + ((g ^ (r & 7)) << 3)];
            }
#pragma unroll
            for (int rb = 0; rb < 4; rb++)
#pragma unroll
                for (int cb = 0; cb < 4; cb++)
                    acc[rb][cb] = __builtin_amdgcn_mfma_f32_16x16x32_bf16(
                        af[rb], bfr[cb], acc[rb][cb], 0, 0, 0);
        }
    }

    __hip_bfloat16* cbp = (__hip_bfloat16*)Cb;
#pragma unroll
    for (int cb = 0; cb < 4; cb++) {
        int col = col0 + wn0 + cb * 16 + m16;
        float bvv = bias ? bias[col] : 0.f;
#pragma unroll
        for (int rb = 0; rb < 4; rb++) {
            int rbase = row0 + wm0 + rb * 16 + quad * 4;
#pragma unroll
            for (int r = 0; r < 4; r++) {
                size_t off = (size_t)(rbase + r) * ldc + col;
                float v = acc[rb][cb][r] + bvv;
                if (act) v = 0.5f * v * (1.f + erff(v * 0.70710678118654752f));
                if (res) v += res[off];
                if (Cf) Cf[off] = v;
                else    cbp[off] = __float2bfloat16(v);
            }
        }
    }
}

// ---------------------------------------------------------------------------
// fused flash attention. Block = 128 Q-rows of one (chunk, head) pair;
// 4 waves x 32 Q-rows. K-tiles of 64 keys, online softmax, P via LDS
// round-trip (C-layout -> A-layout). grid (4, NPAIR).
// ---------------------------------------------------------------------------
__global__ __launch_bounds__(256) void flash_attn(
    const short* __restrict__ qkv, const short* __restrict__ vt,
    const float* __restrict__ bmask, short* __restrict__ ctxb)
{
    __shared__ __align__(16) short Kt[64 * 64];
    __shared__ __align__(16) short Vt[64 * 64];
    __shared__ __align__(16) short Pt[128 * 64];

    const int pair = blockIdx.y, chunk = pair / 12, head = pair % 12;
    const int q0 = blockIdx.x * 128;
    const int tid = threadIdx.x;
    const int w = tid >> 6, l = tid & 63;
    const int lr = l >> 3, lc = l & 7, lcs = lc ^ lr;
    const int quad = l >> 4, m16 = l & 15;

    const short* Qbase = qkv + (size_t)(chunk * SCH + q0) * DQKV + head * 64;
    const short* Kbase = qkv + 768 + (size_t)(chunk * SCH) * DQKV + head * 64;
    const short* Vbase = vt + (size_t)pair * 64 * SCH;
    const float* mrow = bmask + chunk * SCH;

    // stage Q (each wave stages exactly its own 32 rows) into Pt
#pragma unroll
    for (int i = 0; i < 4; i++) {
        int ch = w * 4 + i;
        g2l16(Qbase + (size_t)(ch * 8 + lr) * DQKV + lcs * 8, &Pt[ch * 512 + l * 8]);
    }
    __syncthreads();
    v8bf qf[2][2];
#pragma unroll
    for (int rb = 0; rb < 2; rb++) {
        int r = w * 32 + rb * 16 + m16;
#pragma unroll
        for (int ks = 0; ks < 2; ks++) {
            int g = ks * 4 + quad;
            qf[rb][ks] = *(const v8bf*)&Pt[r * 64 + ((g ^ (r & 7)) << 3)];
        }
    }

    f32x4 accO[2][4] = {};
    float m_i[2][4], l_i[2][4];
#pragma unroll
    for (int rb = 0; rb < 2; rb++)
#pragma unroll
        for (int r = 0; r < 4; r++) { m_i[rb][r] = -1e30f; l_i[rb][r] = 0.f; }

    for (int t0 = 0; t0 < SCH; t0 += 64) {
        __syncthreads();     // all waves done reading Kt/Vt (and Pt as Q)
#pragma unroll
        for (int i = 0; i < 2; i++) {
            int ch = w * 2 + i;
            g2l16(Kbase + (size_t)(t0 + ch * 8 + lr) * DQKV + lcs * 8,
                  &Kt[ch * 512 + l * 8]);
            g2l16(Vbase + (size_t)(ch * 8 + lr) * SCH + t0 + lcs * 8,
                  &Vt[ch * 512 + l * 8]);
        }
        __syncthreads();     // staging complete

        float mb[4];
#pragma unroll
        for (int cb = 0; cb < 4; cb++)
            mb[cb] = (1.f - mrow[t0 + cb * 16 + m16]) * -10000.f;

        // S = Q K^T (this wave: 32 rows x 64 keys)
        f32x4 accS[2][4] = {};
#pragma unroll
        for (int ks = 0; ks < 2; ks++) {
            int g = ks * 4 + quad;
            v8bf kf[4];
#pragma unroll
            for (int cb = 0; cb < 4; cb++) {
                int r = cb * 16 + m16;
                kf[cb] = *(const v8bf*)&Kt[r * 64 + ((g ^ (r & 7)) << 3)];
            }
#pragma unroll
            for (int rb = 0; rb < 2; rb++)
#pragma unroll
                for (int cb = 0; cb < 4; cb++)
                    accS[rb][cb] = __builtin_amdgcn_mfma_f32_16x16x32_bf16(
                        qf[rb][ks], kf[cb], accS[rb][cb], 0, 0, 0);
        }

        // online softmax (rows live across the 16 m16-lanes of each quad)
#pragma unroll
        for (int rb = 0; rb < 2; rb++) {
#pragma unroll
            for (int r = 0; r < 4; r++) {
                float mx = -1e30f;
#pragma unroll
                for (int cb = 0; cb < 4; cb++) {
                    float sv = accS[rb][cb][r] * 0.125f + mb[cb];
                    accS[rb][cb][r] = sv;
                    mx = fmaxf(mx, sv);
                }
#pragma unroll
                for (int x = 1; x < 16; x <<= 1)
                    mx = fmaxf(mx, __shfl_xor(mx, x, 64));
                float mnew = fmaxf(m_i[rb][r], mx);
                float alpha = expf(m_i[rb][r] - mnew);
                m_i[rb][r] = mnew;
                float rs = 0.f;
#pragma unroll
                for (int cb = 0; cb < 4; cb++) {
                    float p = expf(accS[rb][cb][r] - mnew);
                    accS[rb][cb][r] = p;
                    rs += p;
                }
#pragma unroll
                for (int x = 1; x < 16; x <<= 1)
                    rs += __shfl_xor(rs, x, 64);
                l_i[rb][r] = l_i[rb][r] * alpha + rs;
#pragma unroll
                for (int cb = 0; cb < 4; cb++)
                    accO[rb][cb][r] *= alpha;
            }
        }

        // P -> LDS (C-layout values into swizzled A-layout rows; own rows only)
        __hip_bfloat16* ptb = (__hip_bfloat16*)Pt;
#pragma unroll
        for (int rb = 0; rb < 2; rb++)
#pragma unroll
            for (int cb = 0; cb < 4; cb++) {
                int kg = cb * 2 + (m16 >> 3), j = m16 & 7;
#pragma unroll
                for (int r = 0; r < 4; r++) {
                    int row = w * 32 + rb * 16 + quad * 4 + r;
                    ptb[row * 64 + ((kg ^ (row & 7)) << 3) + j] =
                        __float2bfloat16(accS[rb][cb][r]);
                }
            }

        // O += P V  (A-frags from own Pt rows; B-frags from Vt)
#pragma unroll
        for (int ks = 0; ks < 2; ks++) {
            int g = ks * 4 + quad;
            v8bf vf[4], pf[2];
#pragma unroll
            for (int cb = 0; cb < 4; cb++) {
                int r = cb * 16 + m16;
                vf[cb] = *(const v8bf*)&Vt[r * 64 + ((g ^ (r & 7)) << 3)];
            }
#pragma unroll
            for (int rb = 0; rb < 2; rb++) {
                int r = w * 32 + rb * 16 + m16;
                pf[rb] = *(const v8bf*)&Pt[r * 64 + ((g ^ (r & 7)) << 3)];
            }
#pragma unroll
            for (int rb = 0; rb < 2; rb++)
#pragma unroll
                for (int cb = 0; cb < 4; cb++)
                    accO[rb][cb] = __builtin_amdgcn_mfma_f32_16x16x32_bf16(
                        pf[rb], vf[cb], accO[rb][cb], 0, 0, 0);
        }
    }

    // write O / l  -> ctxb[chunk*512+row][head*64+d] (bf16)
    __hip_bfloat16* ob = (__hip_bfloat16*)ctxb;
#pragma unroll
    for (int rb = 0; rb < 2; rb++)
#pragma unroll
        for (int r = 0; r < 4; r++) {
            int row = q0 + w * 32 + rb * 16 + quad * 4 + r;
            float inv = 1.f / l_i[rb][r];
            size_t base = (size_t)(chunk * SCH + row) * DM + head * 64;
#pragma unroll
            for (int cb = 0; cb < 4; cb++)
                ob[base + cb * 16 + m16] = __float2bfloat16(accO[rb][cb][r] * inv);
        }
}

// ---------------------------------------------------------------------------
// V transpose: qkv v-section -> vt[(pair*64 + d)*512 + t]
// ---------------------------------------------------------------------------
__global__ __launch_bounds__(256) void transpose_v(
    const short* __restrict__ qkv, short* __restrict__ vt)
{
    int pair = blockIdx.y, chunk = pair / 12, head = pair % 12;
    int t0 = blockIdx.x * 64;
    __shared__ short s[64][68];
    int tr = threadIdx.x >> 4;
    int tc = (threadIdx.x & 15) * 4;
    const short* src = qkv + 1536 + (size_t)(chunk * SCH + t0) * DQKV + head * 64;
#pragma unroll
    for (int i = 0; i < 4; i++) {
        int t = tr + i * 16;
        ushort4 u = *(const ushort4*)(src + (size_t)t * DQKV + tc);
        s[t][tc] = u.x; s[t][tc + 1] = u.y; s[t][tc + 2] = u.z; s[t][tc + 3] = u.w;
    }
    __syncthreads();
    short* dst = vt + (size_t)pair * 64 * SCH + t0;
#pragma unroll
    for (int i = 0; i < 4; i++) {
        int d = tr + i * 16;
        ushort4 o;
        o.x = s[tc][d]; o.y = s[tc + 1][d]; o.z = s[tc + 2][d]; o.w = s[tc + 3][d];
        *(ushort4*)(dst + (size_t)d * SCH + tc) = o;
    }
}

// ---------------------------------------------------------------------------
// offset mean pooling over fp32 h
// ---------------------------------------------------------------------------
__global__ __launch_bounds__(256) void pool_kernel(
    const float* __restrict__ h, const int* __restrict__ offs,
    const int* __restrict__ wmask, float* __restrict__ out)
{
    int bw = blockIdx.x;
    int b = bw >> 9;
    int st = offs[bw * 2], ed = offs[bw * 2 + 1];
    bool valid = (wmask[bw] != 0) && (st < ed);
    float* orow = out + (size_t)bw * DM;
    float inv = valid ? 1.f / (float)(ed - st) : 0.f;
#pragma unroll
    for (int i = 0; i < 3; i++) {
        int d = threadIdx.x + i * 256;
        float s = 0.f;
        if (valid) {
            for (int t = st; t < ed; t++)
                s += h[((size_t)b * 1024 + t) * DM + d];
            s *= inv;
        }
        orow[d] = s;
    }
}

// ---------------------------------------------------------------------------
// host pipeline
// ---------------------------------------------------------------------------
extern "C" void kernel_launch(void* const* d_in, const int* in_sizes, int n_in,
                              void* d_out, int out_size, void* d_ws, size_t ws_size,
                              hipStream_t stream) {
    const int*   x_bert   = (const int*)  d_in[0];
    const float* x_bmask  = (const float*)d_in[1];
    const int*   x_offset = (const int*)  d_in[2];
    const int*   x_wmask  = (const int*)  d_in[3];
    const float* wemb     = (const float*)d_in[4];
    const float* pemb     = (const float*)d_in[5];
    const float* temb     = (const float*)d_in[6];
    const float* emb_g    = (const float*)d_in[7];
    const float* emb_b    = (const float*)d_in[8];
    const float* Wq  = (const float*)d_in[9];
    const float* bq  = (const float*)d_in[10];
    const float* Wk  = (const float*)d_in[11];
    const float* bk  = (const float*)d_in[12];
    const float* Wv  = (const float*)d_in[13];
    const float* bv  = (const float*)d_in[14];
    const float* Wo  = (const float*)d_in[15];
    const float* bo  = (const float*)d_in[16];
    const float* ln1g = (const float*)d_in[17];
    const float* ln1b = (const float*)d_in[18];
    const float* W1  = (const float*)d_in[19];
    const float* b1f = (const float*)d_in[20];
    const float* W2  = (const float*)d_in[21];
    const float* b2f = (const float*)d_in[22];
    const float* ln2g = (const float*)d_in[23];
    const float* ln2b = (const float*)d_in[24];
    float* out = (float*)d_out;

    float *h, *h1, *tmp, *bqkv;
    short *hb, *h1b, *qkv, *ctxb, *ffb, *vt, *wqkvT, *woT, *w1T, *w2T;
    hipGetSymbolAddress((void**)&h,    HIP_SYMBOL(g_h));
    hipGetSymbolAddress((void**)&h1,   HIP_SYMBOL(g_h1));
    hipGetSymbolAddress((void**)&tmp,  HIP_SYMBOL(g_tmp));
    hipGetSymbolAddress((void**)&hb,   HIP_SYMBOL(g_hb));
    hipGetSymbolAddress((void**)&h1b,  HIP_SYMBOL(g_h1b));
    hipGetSymbolAddress((void**)&qkv,  HIP_SYMBOL(g_qkv));
    hipGetSymbolAddress((void**)&ctxb, HIP_SYMBOL(g_ctxb));
    hipGetSymbolAddress((void**)&ffb,  HIP_SYMBOL(g_ffb));
    hipGetSymbolAddress((void**)&vt,   HIP_SYMBOL(g_vt));
    hipGetSymbolAddress((void**)&wqkvT,HIP_SYMBOL(g_wqkvT));
    hipGetSymbolAddress((void**)&woT,  HIP_SYMBOL(g_woT));
    hipGetSymbolAddress((void**)&w1T,  HIP_SYMBOL(g_w1T));
    hipGetSymbolAddress((void**)&w2T,  HIP_SYMBOL(g_w2T));
    hipGetSymbolAddress((void**)&bqkv, HIP_SYMBOL(g_bqkv));

    // ---- weight prep ----
    dim3 wtA(DM / 32, DM / 32, 4);
    wconv<<<wtA, 256, 0, stream>>>(Wq, wqkvT,             DM, DM, (long long)DM * DM, (long long)DQKV * DM);
    wconv<<<wtA, 256, 0, stream>>>(Wk, wqkvT + 768 * DM,  DM, DM, (long long)DM * DM, (long long)DQKV * DM);
    wconv<<<wtA, 256, 0, stream>>>(Wv, wqkvT + 1536 * DM, DM, DM, (long long)DM * DM, (long long)DQKV * DM);
    wconv<<<wtA, 256, 0, stream>>>(Wo, woT,               DM, DM, (long long)DM * DM, (long long)DM * DM);
    dim3 wtB(DF / 32, DM / 32, 4);
    wconv<<<wtB, 256, 0, stream>>>(W1, w1T, DM, DF, (long long)DM * DF, (long long)DF * DM);
    dim3 wtC(DM / 32, DF / 32, 4);
    wconv<<<wtC, 256, 0, stream>>>(W2, w2T, DF, DM, (long long)DF * DM, (long long)DM * DF);
    concat_bias<<<(4 * DQKV + 255) / 256, 256, 0, stream>>>(bq, bk, bv, bqkv);

    // ---- embedding ----
    embed_ln_kernel<<<TOK, 256, 0, stream>>>(x_bert, wemb, pemb, temb, emb_g, emb_b, h, hb);

    for (int l = 0; l < 4; l++) {
        const short* wqkvl = wqkvT + (size_t)l * DQKV * DM;
        const short* wol   = woT  + (size_t)l * DM * DM;
        const short* w1l   = w1T  + (size_t)l * DF * DM;
        const short* w2l   = w2T  + (size_t)l * DM * DF;

        // fused QKV projection -> bf16 qkv
        mfma_gemm<<<dim3(DQKV / 128, TOK / 128), 256, 0, stream>>>(
            hb, DM, wqkvl, DM, bqkv + l * DQKV, nullptr,
            nullptr, qkv, DQKV, DM, 0);

        transpose_v<<<dim3(8, NPAIR), 256, 0, stream>>>(qkv, vt);

        // fused attention -> bf16 ctxb
        flash_attn<<<dim3(4, NPAIR), 256, 0, stream>>>(qkv, vt, x_bmask, ctxb);

        // output projection + residual -> fp32 tmp; then LN1
        mfma_gemm<<<dim3(DM / 128, TOK / 128), 256, 0, stream>>>(
            ctxb, DM, wol, DM, bo + (size_t)l * DM, h,
            tmp, nullptr, DM, DM, 0);
        ln_kernel<<<TOK, 256, 0, stream>>>(tmp, ln1g + (size_t)l * DM, ln1b + (size_t)l * DM, h1, h1b);

        // FFN1 (+gelu) -> bf16 ffb
        mfma_gemm<<<dim3(DF / 128, TOK / 128), 256, 0, stream>>>(
            h1b, DM, w1l, DM, b1f + (size_t)l * DF, nullptr,
            nullptr, ffb, DF, DM, 1);
        // FFN2 + residual -> fp32 tmp; then LN2
        mfma_gemm<<<dim3(DM / 128, TOK / 128), 256, 0, stream>>>(
            ffb, DF, w2l, DF, b2f + (size_t)l * DM, h1,
            tmp, nullptr, DM, DF, 0);
        ln_kernel<<<TOK, 256, 0, stream>>>(tmp, ln2g + (size_t)l * DM, ln2b + (size_t)l * DM, h, hb);
    }

    pool_kernel<<<8 * 512, 256, 0, stream>>>(h, x_offset, x_wmask, out);
}